// Round 10
// baseline (199.706 us; speedup 1.0000x reference)
//
#include <hip/hip_runtime.h>
#include <math.h>

#define NROWS 65536
#define ED 64
#define NE 2048
#define TAU 3e-4f
#define LOG2E 1.44269504089f
#define LN2 0.69314718056f
#define TAUS (TAU * LOG2E)

typedef _Float16 f16x8 __attribute__((ext_vector_type(8)));
typedef float f32x4 __attribute__((ext_vector_type(4)));

// ---- workspace layout (float offsets): total ~2.9MB ----
#define WS_CBH      0        // fp16[2048*64] = 65536 float slots
#define WS_CBT      65536    // float[64*2048] transposed codebook
#define WS_RINV     196608   // float[65536]
#define WS_MROW     262144   // float[65536]
#define WS_IDX      327680   // int[65536]
#define WS_FLAGCNT  393216   // int[1] (+15 pad)
#define WS_COUNTS   393232   // float[2048]   (contiguous with flagcnt: one memset)
#define WS_FLAGLIST 395280   // int[65536]
#define WS_PSUM     460816   // float[2048]
#define WS_MPART    462864   // float[64]
#define WS_PPART    462928   // float[128*2048]

// ---- output layout (float offsets): z_q_st, commit, kl, lb, cb, perplexity ----
#define OUT_ZQ     0
#define OUT_COMMIT 4194304
#define OUT_KL     4194305
#define OUT_LB     4194306
#define OUT_CB     4194307
#define OUT_PERP   4325379

// ---- scratch inside the zq output region (fully overwritten later) ----
#define ZS_ZNORM   0         // fp16[65536*64]  -> 2097152 float slots
#define ZS_PM      2097152   // float[16*65536] -> 1048576 slots
#define ZS_PAUX    3145728   // u16[16*65536]   -> 524288 slots
#define ZS_PSH     3670016   // fp16[16*65536]  -> 524288 slots (ends at 4194304)

__global__ void k_cb(const float* __restrict__ emb, _Float16* __restrict__ cbh,
                     float* __restrict__ cbo, float* __restrict__ cbT) {
    int t = blockIdx.x * blockDim.x + threadIdx.x;
    int row = t >> 6;
    int lane = t & 63;
    if (row >= NE) return;
    float v = emb[row * ED + lane];
    float sq = v * v;
#pragma unroll
    for (int off = 32; off > 0; off >>= 1) sq += __shfl_xor(sq, off);
    float c = v * (1.0f / fmaxf(sqrtf(sq), 1e-12f));
    cbo[row * ED + lane] = c;
    cbh[row * ED + lane] = (_Float16)c;
    cbT[(size_t)lane * NE + row] = c;     // transposed copy for k_recheck
}

// Normalize z rows -> fp16 znorm, PRE-SCALED by log2(e) so exp(d)=v_exp(mfma out).
__global__ void k_prep(const float* __restrict__ z, _Float16* __restrict__ znorm) {
    const int tid = threadIdx.x;
    const int lane = tid & 63;
    const int w = tid >> 6;
    const int row = blockIdx.x * 64 + w * 16 + (lane >> 2);
    const int q = lane & 3;
    const float4* zp = (const float4*)(z + (size_t)row * ED + q * 16);
    const float4 a = zp[0], b = zp[1], c = zp[2], d = zp[3];
    float sq = a.x*a.x + a.y*a.y + a.z*a.z + a.w*a.w
             + b.x*b.x + b.y*b.y + b.z*b.z + b.w*b.w
             + c.x*c.x + c.y*c.y + c.z*c.z + c.w*c.w
             + d.x*d.x + d.y*d.y + d.z*d.z + d.w*d.w;
    sq += __shfl_xor(sq, 1);
    sq += __shfl_xor(sq, 2);
    const float r = LOG2E / fmaxf(sqrtf(sq), 1e-12f);
    f16x8 h0, h1;
    h0[0]=(_Float16)(a.x*r); h0[1]=(_Float16)(a.y*r); h0[2]=(_Float16)(a.z*r); h0[3]=(_Float16)(a.w*r);
    h0[4]=(_Float16)(b.x*r); h0[5]=(_Float16)(b.y*r); h0[6]=(_Float16)(b.z*r); h0[7]=(_Float16)(b.w*r);
    h1[0]=(_Float16)(c.x*r); h1[1]=(_Float16)(c.y*r); h1[2]=(_Float16)(c.z*r); h1[3]=(_Float16)(c.w*r);
    h1[4]=(_Float16)(d.x*r); h1[5]=(_Float16)(d.y*r); h1[6]=(_Float16)(d.z*r); h1[7]=(_Float16)(d.w*r);
    f16x8* dst = (f16x8*)(znorm + (size_t)row * ED + q * 16);
    dst[0] = h0; dst[1] = h1;
}

// Stats kernel: barrier-free, 4-wave blocks for occupancy, 2 row-tiles in flight.
// Wave owns 128 codewords (A-frags resident). Scaled domain: c = d*log2e.
__launch_bounds__(256, 4)
__global__ void k_s1(const _Float16* __restrict__ znorm, const _Float16* __restrict__ cbh,
                     float* __restrict__ pm, unsigned short* __restrict__ paux,
                     _Float16* __restrict__ psh) {
    const int tid = threadIdx.x;
    const int lane = tid & 63;
    const int w = tid >> 6;               // 0..3
    const int l15 = lane & 15;
    const int lg = lane >> 4;
    const int gw = blockIdx.x * 4 + w;    // 0..8191
    const int g = gw & 15;                // codeword group (128 cw)
    const int split = gw >> 4;            // 0..511 (128 rows each)
    const int cwbase = g * 128;

    f16x8 af[8][2];
#pragma unroll
    for (int jf = 0; jf < 8; ++jf) {
        const _Float16* ap = cbh + (size_t)(cwbase + jf * 16 + l15) * ED + lg * 8;
        af[jf][0] = *(const f16x8*)(ap);
        af[jf][1] = *(const f16x8*)(ap + 32);
    }

    for (int t = 0; t < 4; ++t) {
        const int rbA = split * 128 + t * 32;
        const _Float16* bpA = znorm + (size_t)(rbA + l15) * ED + lg * 8;
        const _Float16* bpB = bpA + 16 * ED;
        const f16x8 bA0 = *(const f16x8*)(bpA);
        const f16x8 bA1 = *(const f16x8*)(bpA + 32);
        const f16x8 bB0 = *(const f16x8*)(bpB);
        const f16x8 bB1 = *(const f16x8*)(bpB + 32);
        float mA = -4.f, m2A = -4.f, sA0 = 0.f, sA1 = 0.f;
        float mB = -4.f, m2B = -4.f, sB0 = 0.f, sB1 = 0.f;
        int miA = 0, miB = 0;
#pragma unroll
        for (int jf = 0; jf < 8; ++jf) {
            f32x4 cA = (f32x4){0.f, 0.f, 0.f, 0.f};
            cA = __builtin_amdgcn_mfma_f32_16x16x32_f16(af[jf][0], bA0, cA, 0, 0, 0);
            cA = __builtin_amdgcn_mfma_f32_16x16x32_f16(af[jf][1], bA1, cA, 0, 0, 0);
            f32x4 cB = (f32x4){0.f, 0.f, 0.f, 0.f};
            cB = __builtin_amdgcn_mfma_f32_16x16x32_f16(af[jf][0], bB0, cB, 0, 0, 0);
            cB = __builtin_amdgcn_mfma_f32_16x16x32_f16(af[jf][1], bB1, cB, 0, 0, 0);
            const int cw0 = cwbase + jf * 16 + lg * 4;
#pragma unroll
            for (int i = 0; i < 4; ++i) {
                const float vA = cA[i];
                m2A = fmaxf(m2A, fminf(vA, mA));
                miA = (vA > mA) ? (cw0 + i) : miA;
                mA  = fmaxf(vA, mA);
                const float vB = cB[i];
                m2B = fmaxf(m2B, fminf(vB, mB));
                miB = (vB > mB) ? (cw0 + i) : miB;
                mB  = fmaxf(vB, mB);
                if (i & 1) { sA1 += exp2f(vA); sB1 += exp2f(vB); }
                else       { sA0 += exp2f(vA); sB0 += exp2f(vB); }
            }
        }
        float sA = sA0 + sA1, sB = sB0 + sB1;
#pragma unroll
        for (int d = 16; d <= 32; d <<= 1) {
            float om = __shfl_xor(mA, d);
            float om2 = __shfl_xor(m2A, d);
            int   oi = __shfl_xor(miA, d);
            sA += __shfl_xor(sA, d);
            float nm2 = fmaxf(fmaxf(m2A, om2), fminf(mA, om));
            bool take = (om > mA) || (om == mA && oi < miA);
            miA = take ? oi : miA;  mA = take ? om : mA;  m2A = nm2;
            om = __shfl_xor(mB, d);
            om2 = __shfl_xor(m2B, d);
            oi = __shfl_xor(miB, d);
            sB += __shfl_xor(sB, d);
            nm2 = fmaxf(fmaxf(m2B, om2), fminf(mB, om));
            take = (om > mB) || (om == mB && oi < miB);
            miB = take ? oi : miB;  mB = take ? om : mB;  m2B = nm2;
        }
        if (lane < 16) {
            int row = rbA + lane;
            pm[(size_t)g * NROWS + row] = mA;
            paux[(size_t)g * NROWS + row] =
                (unsigned short)(((mA - m2A < TAUS) ? 2048 : 0) | miA);
            psh[(size_t)g * NROWS + row] = (_Float16)sA;
            row += 16;
            pm[(size_t)g * NROWS + row] = mB;
            paux[(size_t)g * NROWS + row] =
                (unsigned short)(((mB - m2B < TAUS) ? 2048 : 0) | miB);
            psh[(size_t)g * NROWS + row] = (_Float16)sB;
        }
    }
}

// Per-row combine of the 16 group partials (scaled domain; unscale mrow by ln2).
__global__ void k_comb(const float* __restrict__ pm, const unsigned short* __restrict__ paux,
                       const _Float16* __restrict__ psh, float* __restrict__ rinv,
                       float* __restrict__ mrow, int* __restrict__ idxw,
                       int* __restrict__ flagcnt, int* __restrict__ flaglist,
                       float* __restrict__ counts) {
    const int row = blockIdx.x * 256 + threadIdx.x;
    float mg[16];
    unsigned short ax[16];
    float s = 0.f;
#pragma unroll
    for (int g = 0; g < 16; ++g) {
        mg[g] = pm[(size_t)g * NROWS + row];
        ax[g] = paux[(size_t)g * NROWS + row];
        s += (float)psh[(size_t)g * NROWS + row];
    }
    float bm = -4.f; int bi = 0;
#pragma unroll
    for (int g = 0; g < 16; ++g) {
        if (mg[g] > bm) { bm = mg[g]; bi = ax[g] & 2047; }
    }
    int near = 0; bool fl = false;
#pragma unroll
    for (int g = 0; g < 16; ++g) {
        const bool nr = (mg[g] >= bm - TAUS);
        near += nr ? 1 : 0;
        fl = fl || (nr && (ax[g] & 2048));
    }
    rinv[row] = 1.0f / s;
    mrow[row] = bm * LN2;
    idxw[row] = bi;
    if (fl || near >= 2) {
        int e = atomicAdd(flagcnt, 1);
        flaglist[e] = row;
    } else {
        atomicAdd(&counts[bi], 1.0f);
    }
}

// p accumulation: 4-wave blocks; 4 codeword tiles resident, 4 independent chains.
__launch_bounds__(256, 4)
__global__ void k_s2(const _Float16* __restrict__ znorm, const _Float16* __restrict__ cbh,
                     const float* __restrict__ rinv, float* __restrict__ ppart) {
    const int tid = threadIdx.x;
    const int lane = tid & 63;
    const int w = tid >> 6;               // 0..3
    const int l15 = lane & 15;
    const int lg = lane >> 4;
    const int gw = blockIdx.x * 4 + w;    // 0..4095
    const int cwg = gw & 31;              // 64-cw group
    const int split = gw >> 5;            // 0..127 (512 rows each)

    f16x8 bf[4][2];
#pragma unroll
    for (int jf = 0; jf < 4; ++jf) {
        const _Float16* bp = cbh + (size_t)(cwg * 64 + jf * 16 + l15) * ED + lg * 8;
        bf[jf][0] = *(const f16x8*)(bp);
        bf[jf][1] = *(const f16x8*)(bp + 32);
    }
    float pc[4] = {0.f, 0.f, 0.f, 0.f};

    for (int t = 0; t < 32; ++t) {
        const int rowbase = split * 512 + t * 16;
        const _Float16* ap = znorm + (size_t)(rowbase + l15) * ED + lg * 8;
        const f16x8 a0 = *(const f16x8*)(ap);
        const f16x8 a1 = *(const f16x8*)(ap + 32);
        const int r0 = rowbase + lg * 4;
        const float rv0 = rinv[r0], rv1 = rinv[r0 + 1];
        const float rv2 = rinv[r0 + 2], rv3 = rinv[r0 + 3];
#pragma unroll
        for (int jf = 0; jf < 4; ++jf) {
            f32x4 c = (f32x4){0.f, 0.f, 0.f, 0.f};
            c = __builtin_amdgcn_mfma_f32_16x16x32_f16(a0, bf[jf][0], c, 0, 0, 0);
            c = __builtin_amdgcn_mfma_f32_16x16x32_f16(a1, bf[jf][1], c, 0, 0, 0);
            pc[jf] += exp2f(c[0]) * rv0 + exp2f(c[1]) * rv1
                    + exp2f(c[2]) * rv2 + exp2f(c[3]) * rv3;
        }
    }
#pragma unroll
    for (int jf = 0; jf < 4; ++jf) {
        pc[jf] += __shfl_xor(pc[jf], 16);
        pc[jf] += __shfl_xor(pc[jf], 32);
    }
    if (lg == 0) {
        float* pp = ppart + (size_t)split * NE + cwg * 64;
#pragma unroll
        for (int jf = 0; jf < 4; ++jf) pp[jf * 16 + l15] = pc[jf];
    }
}

// z_q gather (fully overwrites the zq scratch region). 16 threads per row.
__global__ void k_zqg(const float* __restrict__ cb32, const int* __restrict__ idxw,
                      float* __restrict__ zq) {
    const int r = blockIdx.x * 16 + (threadIdx.x >> 4);
    const int q = threadIdx.x & 15;
    const int j = idxw[r];
    ((float4*)(zq + (size_t)r * ED))[q] = ((const float4*)(cb32 + (size_t)j * ED))[q];
}

// Exact fp32 re-scan, LDS-tiled mini-GEMM: 8 flagged rows per block-tile.
// Thread t owns codeword columns {q*256+t}; coalesced cbT reads; z in LDS.
__launch_bounds__(256, 4)
__global__ void k_recheck(const float* __restrict__ z, const float* __restrict__ cbT,
                          const float* __restrict__ cb32,
                          const int* __restrict__ flagcnt, const int* __restrict__ flaglist,
                          float* __restrict__ mrow, float* __restrict__ counts,
                          float* __restrict__ zq) {
    __shared__ float zn[8][ED];
    __shared__ int   rowids[8];
    __shared__ float rbv[8][4];
    __shared__ int   rbi[8][4];
    const int n = *flagcnt;
    const int tid = threadIdx.x, lane = tid & 63, wv = tid >> 6;
    for (int base = blockIdx.x * 8; base < n; base += 512 * 8) {
        // ---- load + normalize up to 8 flagged rows (wave wv -> rows 2wv, 2wv+1) ----
#pragma unroll
        for (int rr = wv * 2; rr < wv * 2 + 2; ++rr) {
            const int e = base + rr;
            int row = -1;
            float v = 0.f;
            if (e < n) { row = flaglist[e]; v = z[(size_t)row * ED + lane]; }
            float sq = v * v;
#pragma unroll
            for (int d = 32; d > 0; d >>= 1) sq += __shfl_xor(sq, d);
            zn[rr][lane] = v * (1.0f / fmaxf(sqrtf(sq), 1e-12f));
            if (lane == 0) rowids[rr] = row;
        }
        __syncthreads();                      // (A) zn/rowids ready
        // ---- accumulate 8 rows x 8 columns per thread ----
        float acc[8][8];
#pragma unroll
        for (int r = 0; r < 8; ++r)
#pragma unroll
            for (int q = 0; q < 8; ++q) acc[r][q] = 0.f;
        for (int k = 0; k < ED; ++k) {
            float cv[8];
            const float* cr = cbT + (size_t)k * NE + tid;
#pragma unroll
            for (int q = 0; q < 8; ++q) cv[q] = cr[q * 256];
#pragma unroll
            for (int r = 0; r < 8; ++r) {
                const float zk = zn[r][k];
#pragma unroll
                for (int q = 0; q < 8; ++q)
                    acc[r][q] = fmaf(zk, cv[q], acc[r][q]);
            }
        }
        // ---- per-row argmax: thread-local over 8 cols, then wave, then block ----
#pragma unroll
        for (int r = 0; r < 8; ++r) {
            float best = -2.f; int bj = 0;
#pragma unroll
            for (int q = 0; q < 8; ++q) {     // ascending j per thread
                const float vv = acc[r][q];
                const int j = q * 256 + tid;
                bj = (vv > best) ? j : bj;
                best = fmaxf(vv, best);
            }
#pragma unroll
            for (int d = 1; d < 64; d <<= 1) {
                const float o = __shfl_xor(best, d);
                const int oj = __shfl_xor(bj, d);
                const bool tk = (o > best) || (o == best && oj < bj);
                best = tk ? o : best;
                bj = tk ? oj : bj;
            }
            if (lane == 0) { rbv[r][wv] = best; rbi[r][wv] = bj; }
        }
        __syncthreads();                      // (B) wave partials ready
        if (wv == 0 && lane < 8) {
            const int r = lane;
            float bv = rbv[r][0]; int bj = rbi[r][0];
#pragma unroll
            for (int u = 1; u < 4; ++u) {
                const float o = rbv[r][u]; const int oj = rbi[r][u];
                const bool tk = (o > bv) || (o == bv && oj < bj);
                bv = tk ? o : bv; bj = tk ? oj : bj;
            }
            rbi[r][0] = bj;                   // publish final
            const int row = rowids[r];
            if (row >= 0) {
                mrow[row] = bv;
                atomicAdd(&counts[bj], 1.0f);
            }
        }
        __syncthreads();                      // (C) final selection ready
        // ---- rewrite z_q rows (wave wv -> rows 2wv, 2wv+1) ----
#pragma unroll
        for (int rr = wv * 2; rr < wv * 2 + 2; ++rr) {
            const int row = rowids[rr];
            if (row >= 0) {
                const int bj = rbi[rr][0];
                zq[(size_t)row * ED + lane] = cb32[(size_t)bj * ED + lane];
            }
        }
    }
}

// Reductions: blocks 0..7 sum ppart columns (128 slices); blocks 8..71 sum mrow.
__global__ void k_red(const float* __restrict__ ppart, const float* __restrict__ mrow,
                      float* __restrict__ psum, float* __restrict__ mpart) {
    const int tid = threadIdx.x;
    if (blockIdx.x < 8) {
        const int col = blockIdx.x * 256 + tid;
        float s = 0.f;
        for (int sl = 0; sl < 128; ++sl) s += ppart[(size_t)sl * NE + col];
        psum[col] = s;
    } else {
        __shared__ float lds[4];
        const int b = blockIdx.x - 8;     // 0..63
        const int r0 = b * 1024;
        float s = 0.f;
        for (int r = r0 + tid; r < r0 + 1024; r += 256) s += mrow[r];
        const int lane = tid & 63, wv = tid >> 6;
#pragma unroll
        for (int d = 32; d > 0; d >>= 1) s += __shfl_xor(s, d);
        if (lane == 0) lds[wv] = s;
        __syncthreads();
        if (tid == 0) mpart[b] = lds[0] + lds[1] + lds[2] + lds[3];
    }
}

__device__ __forceinline__ float block_reduce_1024(float v, float* lds, int lane, int wid) {
#pragma unroll
    for (int off = 32; off > 0; off >>= 1) v += __shfl_xor(v, off);
    if (lane == 0) lds[wid] = v;
    __syncthreads();
    float r = 0.f;
    if (wid == 0) {
        r = (lane < 16) ? lds[lane] : 0.f;
#pragma unroll
        for (int off = 8; off > 0; off >>= 1) r += __shfl_xor(r, off);
    }
    __syncthreads();
    return r;
}

__global__ void k_final(const float* __restrict__ counts, const float* __restrict__ psum,
                        const float* __restrict__ mpart, float* __restrict__ out) {
    __shared__ float lds[16];
    const int tid = threadIdx.x;          // 1024
    const int lane = tid & 63, wid = tid >> 6;
    float sm = (tid < 64) ? mpart[tid] : 0.f;
    float kl = 0.f, lb = 0.f, H = 0.f;
    const float LOGNE = logf((float)NE);
    for (int j = tid; j < NE; j += 1024) {
        const float p = psum[j] * (1.0f / NROWS);
        const float em = counts[j] * (1.0f / NROWS);
        kl += p * (logf(p) + LOGNE);
        lb += em * p;
        H += em * logf(em + 1e-6f);
    }
    sm = block_reduce_1024(sm, lds, lane, wid);
    kl = block_reduce_1024(kl, lds, lane, wid);
    lb = block_reduce_1024(lb, lds, lane, wid);
    H  = block_reduce_1024(H,  lds, lane, wid);
    if (tid == 0) {
        out[OUT_COMMIT] = 1.25f * (1.0f - sm * (1.0f / NROWS));
        out[OUT_KL] = kl;
        out[OUT_LB] = lb;
        out[OUT_PERP] = expf(-H);
    }
}

extern "C" void kernel_launch(void* const* d_in, const int* in_sizes, int n_in,
                              void* d_out, int out_size, void* d_ws, size_t ws_size,
                              hipStream_t stream) {
    const float* z   = (const float*)d_in[0];
    const float* emb = (const float*)d_in[1];
    float* out = (float*)d_out;
    float* ws  = (float*)d_ws;

    _Float16* cbh  = (_Float16*)(ws + WS_CBH);
    float* cbT     = ws + WS_CBT;
    float* rinv    = ws + WS_RINV;
    float* mrowp   = ws + WS_MROW;
    int* idxw      = (int*)(ws + WS_IDX);
    int* flagcnt   = (int*)(ws + WS_FLAGCNT);
    int* flaglist  = (int*)(ws + WS_FLAGLIST);
    float* counts  = ws + WS_COUNTS;
    float* psum    = ws + WS_PSUM;
    float* mpart   = ws + WS_MPART;
    float* ppart   = ws + WS_PPART;
    float* cb32    = out + OUT_CB;
    float* zq      = out + OUT_ZQ;

    // scratch aliased into the zq output region (overwritten by k_zqg/k_recheck)
    _Float16* znorm      = (_Float16*)(zq + ZS_ZNORM);
    float* pm            = zq + ZS_PM;
    unsigned short* paux = (unsigned short*)(zq + ZS_PAUX);
    _Float16* psh        = (_Float16*)(zq + ZS_PSH);

    // flagcnt + counts are contiguous: single memset
    hipMemsetAsync(flagcnt, 0, (16 + NE) * sizeof(float), stream);

    k_cb      <<<512, 256, 0, stream>>>(emb, cbh, cb32, cbT);
    k_prep    <<<1024, 256, 0, stream>>>(z, znorm);
    k_s1      <<<2048, 256, 0, stream>>>(znorm, cbh, pm, paux, psh);
    k_comb    <<<256, 256, 0, stream>>>(pm, paux, psh, rinv, mrowp, idxw,
                                        flagcnt, flaglist, counts);
    k_s2      <<<1024, 256, 0, stream>>>(znorm, cbh, rinv, ppart);
    k_zqg     <<<4096, 256, 0, stream>>>(cb32, idxw, zq);
    k_recheck <<<512, 256, 0, stream>>>(z, cbT, cb32, flagcnt, flaglist,
                                        mrowp, counts, zq);
    k_red     <<<72, 256, 0, stream>>>(ppart, mrowp, psum, mpart);
    k_final   <<<1, 1024, 0, stream>>>(counts, psum, mpart, out);
}

// Round 11
// 179.683 us; speedup vs baseline: 1.1114x; 1.1114x over previous
//
#include <hip/hip_runtime.h>
#include <math.h>

#define NROWS 65536
#define ED 64
#define NE 2048
#define TAU 3e-4f
#define LOG2E 1.44269504089f
#define LN2 0.69314718056f
#define TAUS (TAU * LOG2E)

typedef _Float16 f16x8 __attribute__((ext_vector_type(8)));
typedef float f32x4 __attribute__((ext_vector_type(4)));

// ---- workspace layout (float offsets): total ~2.9MB ----
#define WS_CBH      0        // fp16[2048*64] = 65536 float slots
#define WS_CBT      65536    // float[64*2048] transposed codebook
#define WS_RINV     196608   // float[65536]
#define WS_MROW     262144   // float[65536]
#define WS_IDX      327680   // int[65536]
#define WS_FLAGCNT  393216   // int[1] (+15 pad)
#define WS_COUNTS   393232   // float[2048]   (contiguous with flagcnt: one memset)
#define WS_FLAGLIST 395280   // int[65536]
#define WS_PSUM     460816   // float[2048]
#define WS_MPART    462864   // float[64]
#define WS_PPART    462928   // float[128*2048]

// ---- output layout (float offsets): z_q_st, commit, kl, lb, cb, perplexity ----
#define OUT_ZQ     0
#define OUT_COMMIT 4194304
#define OUT_KL     4194305
#define OUT_LB     4194306
#define OUT_CB     4194307
#define OUT_PERP   4325379

// ---- scratch inside the zq output region (fully overwritten later) ----
#define ZS_ZNORM   0         // fp16[65536*64]  -> 2097152 float slots
#define ZS_PM      2097152   // float[16*65536] -> 1048576 slots
#define ZS_PAUX    3145728   // u16[16*65536]   -> 524288 slots
#define ZS_PSH     3670016   // fp16[16*65536]  -> 524288 slots (ends at 4194304)

__global__ void k_cb(const float* __restrict__ emb, _Float16* __restrict__ cbh,
                     float* __restrict__ cbo, float* __restrict__ cbT) {
    int t = blockIdx.x * blockDim.x + threadIdx.x;
    int row = t >> 6;
    int lane = t & 63;
    if (row >= NE) return;
    float v = emb[row * ED + lane];
    float sq = v * v;
#pragma unroll
    for (int off = 32; off > 0; off >>= 1) sq += __shfl_xor(sq, off);
    float c = v * (1.0f / fmaxf(sqrtf(sq), 1e-12f));
    cbo[row * ED + lane] = c;
    cbh[row * ED + lane] = (_Float16)c;
    cbT[(size_t)lane * NE + row] = c;     // transposed copy for k_recheck
}

// Normalize z rows -> fp16 znorm, PRE-SCALED by log2(e) so exp(d)=v_exp(mfma out).
__global__ void k_prep(const float* __restrict__ z, _Float16* __restrict__ znorm) {
    const int tid = threadIdx.x;
    const int lane = tid & 63;
    const int w = tid >> 6;
    const int row = blockIdx.x * 64 + w * 16 + (lane >> 2);
    const int q = lane & 3;
    const float4* zp = (const float4*)(z + (size_t)row * ED + q * 16);
    const float4 a = zp[0], b = zp[1], c = zp[2], d = zp[3];
    float sq = a.x*a.x + a.y*a.y + a.z*a.z + a.w*a.w
             + b.x*b.x + b.y*b.y + b.z*b.z + b.w*b.w
             + c.x*c.x + c.y*c.y + c.z*c.z + c.w*c.w
             + d.x*d.x + d.y*d.y + d.z*d.z + d.w*d.w;
    sq += __shfl_xor(sq, 1);
    sq += __shfl_xor(sq, 2);
    const float r = LOG2E / fmaxf(sqrtf(sq), 1e-12f);
    f16x8 h0, h1;
    h0[0]=(_Float16)(a.x*r); h0[1]=(_Float16)(a.y*r); h0[2]=(_Float16)(a.z*r); h0[3]=(_Float16)(a.w*r);
    h0[4]=(_Float16)(b.x*r); h0[5]=(_Float16)(b.y*r); h0[6]=(_Float16)(b.z*r); h0[7]=(_Float16)(b.w*r);
    h1[0]=(_Float16)(c.x*r); h1[1]=(_Float16)(c.y*r); h1[2]=(_Float16)(c.z*r); h1[3]=(_Float16)(c.w*r);
    h1[4]=(_Float16)(d.x*r); h1[5]=(_Float16)(d.y*r); h1[6]=(_Float16)(d.z*r); h1[7]=(_Float16)(d.w*r);
    f16x8* dst = (f16x8*)(znorm + (size_t)row * ED + q * 16);
    dst[0] = h0; dst[1] = h1;
}

// Stats kernel: barrier-free, 4-wave blocks, cap 85 (no spill at 84 natural).
// Wave owns 128 codewords (A-frags resident). Scaled domain: c = d*log2e.
__launch_bounds__(256, 3)
__global__ void k_s1(const _Float16* __restrict__ znorm, const _Float16* __restrict__ cbh,
                     float* __restrict__ pm, unsigned short* __restrict__ paux,
                     _Float16* __restrict__ psh) {
    const int tid = threadIdx.x;
    const int lane = tid & 63;
    const int w = tid >> 6;               // 0..3
    const int l15 = lane & 15;
    const int lg = lane >> 4;
    const int gw = blockIdx.x * 4 + w;    // 0..8191
    const int g = gw & 15;                // codeword group (128 cw)
    const int split = gw >> 4;            // 0..511 (128 rows each)
    const int cwbase = g * 128;

    f16x8 af[8][2];
#pragma unroll
    for (int jf = 0; jf < 8; ++jf) {
        const _Float16* ap = cbh + (size_t)(cwbase + jf * 16 + l15) * ED + lg * 8;
        af[jf][0] = *(const f16x8*)(ap);
        af[jf][1] = *(const f16x8*)(ap + 32);
    }

    for (int t = 0; t < 4; ++t) {
        const int rbA = split * 128 + t * 32;
        const _Float16* bpA = znorm + (size_t)(rbA + l15) * ED + lg * 8;
        const _Float16* bpB = bpA + 16 * ED;
        const f16x8 bA0 = *(const f16x8*)(bpA);
        const f16x8 bA1 = *(const f16x8*)(bpA + 32);
        const f16x8 bB0 = *(const f16x8*)(bpB);
        const f16x8 bB1 = *(const f16x8*)(bpB + 32);
        float mA = -4.f, m2A = -4.f, sA0 = 0.f, sA1 = 0.f;
        float mB = -4.f, m2B = -4.f, sB0 = 0.f, sB1 = 0.f;
        int miA = 0, miB = 0;
#pragma unroll
        for (int jf = 0; jf < 8; ++jf) {
            f32x4 cA = (f32x4){0.f, 0.f, 0.f, 0.f};
            cA = __builtin_amdgcn_mfma_f32_16x16x32_f16(af[jf][0], bA0, cA, 0, 0, 0);
            cA = __builtin_amdgcn_mfma_f32_16x16x32_f16(af[jf][1], bA1, cA, 0, 0, 0);
            f32x4 cB = (f32x4){0.f, 0.f, 0.f, 0.f};
            cB = __builtin_amdgcn_mfma_f32_16x16x32_f16(af[jf][0], bB0, cB, 0, 0, 0);
            cB = __builtin_amdgcn_mfma_f32_16x16x32_f16(af[jf][1], bB1, cB, 0, 0, 0);
            const int cw0 = cwbase + jf * 16 + lg * 4;
#pragma unroll
            for (int i = 0; i < 4; ++i) {
                const float vA = cA[i];
                m2A = fmaxf(m2A, fminf(vA, mA));
                miA = (vA > mA) ? (cw0 + i) : miA;
                mA  = fmaxf(vA, mA);
                const float vB = cB[i];
                m2B = fmaxf(m2B, fminf(vB, mB));
                miB = (vB > mB) ? (cw0 + i) : miB;
                mB  = fmaxf(vB, mB);
                if (i & 1) { sA1 += exp2f(vA); sB1 += exp2f(vB); }
                else       { sA0 += exp2f(vA); sB0 += exp2f(vB); }
            }
        }
        float sA = sA0 + sA1, sB = sB0 + sB1;
#pragma unroll
        for (int d = 16; d <= 32; d <<= 1) {
            float om = __shfl_xor(mA, d);
            float om2 = __shfl_xor(m2A, d);
            int   oi = __shfl_xor(miA, d);
            sA += __shfl_xor(sA, d);
            float nm2 = fmaxf(fmaxf(m2A, om2), fminf(mA, om));
            bool take = (om > mA) || (om == mA && oi < miA);
            miA = take ? oi : miA;  mA = take ? om : mA;  m2A = nm2;
            om = __shfl_xor(mB, d);
            om2 = __shfl_xor(m2B, d);
            oi = __shfl_xor(miB, d);
            sB += __shfl_xor(sB, d);
            nm2 = fmaxf(fmaxf(m2B, om2), fminf(mB, om));
            take = (om > mB) || (om == mB && oi < miB);
            miB = take ? oi : miB;  mB = take ? om : mB;  m2B = nm2;
        }
        if (lane < 16) {
            int row = rbA + lane;
            pm[(size_t)g * NROWS + row] = mA;
            paux[(size_t)g * NROWS + row] =
                (unsigned short)(((mA - m2A < TAUS) ? 2048 : 0) | miA);
            psh[(size_t)g * NROWS + row] = (_Float16)sA;
            row += 16;
            pm[(size_t)g * NROWS + row] = mB;
            paux[(size_t)g * NROWS + row] =
                (unsigned short)(((mB - m2B < TAUS) ? 2048 : 0) | miB);
            psh[(size_t)g * NROWS + row] = (_Float16)sB;
        }
    }
}

// Per-row combine of the 16 group partials (scaled domain; unscale mrow by ln2).
__global__ void k_comb(const float* __restrict__ pm, const unsigned short* __restrict__ paux,
                       const _Float16* __restrict__ psh, float* __restrict__ rinv,
                       float* __restrict__ mrow, int* __restrict__ idxw,
                       int* __restrict__ flagcnt, int* __restrict__ flaglist,
                       float* __restrict__ counts) {
    const int row = blockIdx.x * 256 + threadIdx.x;
    float mg[16];
    unsigned short ax[16];
    float s = 0.f;
#pragma unroll
    for (int g = 0; g < 16; ++g) {
        mg[g] = pm[(size_t)g * NROWS + row];
        ax[g] = paux[(size_t)g * NROWS + row];
        s += (float)psh[(size_t)g * NROWS + row];
    }
    float bm = -4.f; int bi = 0;
#pragma unroll
    for (int g = 0; g < 16; ++g) {
        if (mg[g] > bm) { bm = mg[g]; bi = ax[g] & 2047; }
    }
    int near = 0; bool fl = false;
#pragma unroll
    for (int g = 0; g < 16; ++g) {
        const bool nr = (mg[g] >= bm - TAUS);
        near += nr ? 1 : 0;
        fl = fl || (nr && (ax[g] & 2048));
    }
    rinv[row] = 1.0f / s;
    mrow[row] = bm * LN2;
    idxw[row] = bi;
    if (fl || near >= 2) {
        int e = atomicAdd(flagcnt, 1);
        flaglist[e] = row;
    } else {
        atomicAdd(&counts[bi], 1.0f);
    }
}

// p accumulation: 4-wave blocks, cap 85; 4 codeword tiles resident, 4 chains.
__launch_bounds__(256, 3)
__global__ void k_s2(const _Float16* __restrict__ znorm, const _Float16* __restrict__ cbh,
                     const float* __restrict__ rinv, float* __restrict__ ppart) {
    const int tid = threadIdx.x;
    const int lane = tid & 63;
    const int w = tid >> 6;               // 0..3
    const int l15 = lane & 15;
    const int lg = lane >> 4;
    const int gw = blockIdx.x * 4 + w;    // 0..4095
    const int cwg = gw & 31;              // 64-cw group
    const int split = gw >> 5;            // 0..127 (512 rows each)

    f16x8 bf[4][2];
#pragma unroll
    for (int jf = 0; jf < 4; ++jf) {
        const _Float16* bp = cbh + (size_t)(cwg * 64 + jf * 16 + l15) * ED + lg * 8;
        bf[jf][0] = *(const f16x8*)(bp);
        bf[jf][1] = *(const f16x8*)(bp + 32);
    }
    float pc[4] = {0.f, 0.f, 0.f, 0.f};

    for (int t = 0; t < 32; ++t) {
        const int rowbase = split * 512 + t * 16;
        const _Float16* ap = znorm + (size_t)(rowbase + l15) * ED + lg * 8;
        const f16x8 a0 = *(const f16x8*)(ap);
        const f16x8 a1 = *(const f16x8*)(ap + 32);
        const int r0 = rowbase + lg * 4;
        const float rv0 = rinv[r0], rv1 = rinv[r0 + 1];
        const float rv2 = rinv[r0 + 2], rv3 = rinv[r0 + 3];
#pragma unroll
        for (int jf = 0; jf < 4; ++jf) {
            f32x4 c = (f32x4){0.f, 0.f, 0.f, 0.f};
            c = __builtin_amdgcn_mfma_f32_16x16x32_f16(a0, bf[jf][0], c, 0, 0, 0);
            c = __builtin_amdgcn_mfma_f32_16x16x32_f16(a1, bf[jf][1], c, 0, 0, 0);
            pc[jf] += exp2f(c[0]) * rv0 + exp2f(c[1]) * rv1
                    + exp2f(c[2]) * rv2 + exp2f(c[3]) * rv3;
        }
    }
#pragma unroll
    for (int jf = 0; jf < 4; ++jf) {
        pc[jf] += __shfl_xor(pc[jf], 16);
        pc[jf] += __shfl_xor(pc[jf], 32);
    }
    if (lg == 0) {
        float* pp = ppart + (size_t)split * NE + cwg * 64;
#pragma unroll
        for (int jf = 0; jf < 4; ++jf) pp[jf * 16 + l15] = pc[jf];
    }
}

// z_q gather (fully overwrites the zq scratch region). 16 threads per row.
__global__ void k_zqg(const float* __restrict__ cb32, const int* __restrict__ idxw,
                      float* __restrict__ zq) {
    const int r = blockIdx.x * 16 + (threadIdx.x >> 4);
    const int q = threadIdx.x & 15;
    const int j = idxw[r];
    ((float4*)(zq + (size_t)r * ED))[q] = ((const float4*)(cb32 + (size_t)j * ED))[q];
}

// Exact fp32 re-scan, LDS-tiled mini-GEMM: 8 flagged rows per block-tile.
// Thread t owns codeword columns {q*256+t}; coalesced cbT reads; z in LDS.
__launch_bounds__(256, 2)
__global__ void k_recheck(const float* __restrict__ z, const float* __restrict__ cbT,
                          const float* __restrict__ cb32,
                          const int* __restrict__ flagcnt, const int* __restrict__ flaglist,
                          float* __restrict__ mrow, float* __restrict__ counts,
                          float* __restrict__ zq) {
    __shared__ float zn[8][ED];
    __shared__ int   rowids[8];
    __shared__ float rbv[8][4];
    __shared__ int   rbi[8][4];
    const int n = *flagcnt;
    const int tid = threadIdx.x, lane = tid & 63, wv = tid >> 6;
    for (int base = blockIdx.x * 8; base < n; base += 512 * 8) {
        // ---- load + normalize up to 8 flagged rows (wave wv -> rows 2wv, 2wv+1) ----
#pragma unroll
        for (int rr = wv * 2; rr < wv * 2 + 2; ++rr) {
            const int e = base + rr;
            int row = -1;
            float v = 0.f;
            if (e < n) { row = flaglist[e]; v = z[(size_t)row * ED + lane]; }
            float sq = v * v;
#pragma unroll
            for (int d = 32; d > 0; d >>= 1) sq += __shfl_xor(sq, d);
            zn[rr][lane] = v * (1.0f / fmaxf(sqrtf(sq), 1e-12f));
            if (lane == 0) rowids[rr] = row;
        }
        __syncthreads();                      // (A) zn/rowids ready
        // ---- accumulate 8 rows x 8 columns per thread ----
        float acc[8][8];
#pragma unroll
        for (int r = 0; r < 8; ++r)
#pragma unroll
            for (int q = 0; q < 8; ++q) acc[r][q] = 0.f;
        for (int k = 0; k < ED; ++k) {
            float cv[8];
            const float* cr = cbT + (size_t)k * NE + tid;
#pragma unroll
            for (int q = 0; q < 8; ++q) cv[q] = cr[q * 256];
#pragma unroll
            for (int r = 0; r < 8; ++r) {
                const float zk = zn[r][k];
#pragma unroll
                for (int q = 0; q < 8; ++q)
                    acc[r][q] = fmaf(zk, cv[q], acc[r][q]);
            }
        }
        // ---- per-row argmax: thread-local over 8 cols, then wave, then block ----
#pragma unroll
        for (int r = 0; r < 8; ++r) {
            float best = -2.f; int bj = 0;
#pragma unroll
            for (int q = 0; q < 8; ++q) {     // ascending j per thread
                const float vv = acc[r][q];
                const int j = q * 256 + tid;
                bj = (vv > best) ? j : bj;
                best = fmaxf(vv, best);
            }
#pragma unroll
            for (int d = 1; d < 64; d <<= 1) {
                const float o = __shfl_xor(best, d);
                const int oj = __shfl_xor(bj, d);
                const bool tk = (o > best) || (o == best && oj < bj);
                best = tk ? o : best;
                bj = tk ? oj : bj;
            }
            if (lane == 0) { rbv[r][wv] = best; rbi[r][wv] = bj; }
        }
        __syncthreads();                      // (B) wave partials ready
        if (wv == 0 && lane < 8) {
            const int r = lane;
            float bv = rbv[r][0]; int bj = rbi[r][0];
#pragma unroll
            for (int u = 1; u < 4; ++u) {
                const float o = rbv[r][u]; const int oj = rbi[r][u];
                const bool tk = (o > bv) || (o == bv && oj < bj);
                bv = tk ? o : bv; bj = tk ? oj : bj;
            }
            rbi[r][0] = bj;                   // publish final
            const int row = rowids[r];
            if (row >= 0) {
                mrow[row] = bv;
                atomicAdd(&counts[bj], 1.0f);
            }
        }
        __syncthreads();                      // (C) final selection ready
        // ---- rewrite z_q rows (wave wv -> rows 2wv, 2wv+1) ----
#pragma unroll
        for (int rr = wv * 2; rr < wv * 2 + 2; ++rr) {
            const int row = rowids[rr];
            if (row >= 0) {
                const int bj = rbi[rr][0];
                zq[(size_t)row * ED + lane] = cb32[(size_t)bj * ED + lane];
            }
        }
    }
}

// Reductions: blocks 0..7 sum ppart columns (128 slices); blocks 8..71 sum mrow.
__global__ void k_red(const float* __restrict__ ppart, const float* __restrict__ mrow,
                      float* __restrict__ psum, float* __restrict__ mpart) {
    const int tid = threadIdx.x;
    if (blockIdx.x < 8) {
        const int col = blockIdx.x * 256 + tid;
        float s = 0.f;
        for (int sl = 0; sl < 128; ++sl) s += ppart[(size_t)sl * NE + col];
        psum[col] = s;
    } else {
        __shared__ float lds[4];
        const int b = blockIdx.x - 8;     // 0..63
        const int r0 = b * 1024;
        float s = 0.f;
        for (int r = r0 + tid; r < r0 + 1024; r += 256) s += mrow[r];
        const int lane = tid & 63, wv = tid >> 6;
#pragma unroll
        for (int d = 32; d > 0; d >>= 1) s += __shfl_xor(s, d);
        if (lane == 0) lds[wv] = s;
        __syncthreads();
        if (tid == 0) mpart[b] = lds[0] + lds[1] + lds[2] + lds[3];
    }
}

__device__ __forceinline__ float block_reduce_1024(float v, float* lds, int lane, int wid) {
#pragma unroll
    for (int off = 32; off > 0; off >>= 1) v += __shfl_xor(v, off);
    if (lane == 0) lds[wid] = v;
    __syncthreads();
    float r = 0.f;
    if (wid == 0) {
        r = (lane < 16) ? lds[lane] : 0.f;
#pragma unroll
        for (int off = 8; off > 0; off >>= 1) r += __shfl_xor(r, off);
    }
    __syncthreads();
    return r;
}

__global__ void k_final(const float* __restrict__ counts, const float* __restrict__ psum,
                        const float* __restrict__ mpart, float* __restrict__ out) {
    __shared__ float lds[16];
    const int tid = threadIdx.x;          // 1024
    const int lane = tid & 63, wid = tid >> 6;
    float sm = (tid < 64) ? mpart[tid] : 0.f;
    float kl = 0.f, lb = 0.f, H = 0.f;
    const float LOGNE = logf((float)NE);
    for (int j = tid; j < NE; j += 1024) {
        const float p = psum[j] * (1.0f / NROWS);
        const float em = counts[j] * (1.0f / NROWS);
        kl += p * (logf(p) + LOGNE);
        lb += em * p;
        H += em * logf(em + 1e-6f);
    }
    sm = block_reduce_1024(sm, lds, lane, wid);
    kl = block_reduce_1024(kl, lds, lane, wid);
    lb = block_reduce_1024(lb, lds, lane, wid);
    H  = block_reduce_1024(H,  lds, lane, wid);
    if (tid == 0) {
        out[OUT_COMMIT] = 1.25f * (1.0f - sm * (1.0f / NROWS));
        out[OUT_KL] = kl;
        out[OUT_LB] = lb;
        out[OUT_PERP] = expf(-H);
    }
}

extern "C" void kernel_launch(void* const* d_in, const int* in_sizes, int n_in,
                              void* d_out, int out_size, void* d_ws, size_t ws_size,
                              hipStream_t stream) {
    const float* z   = (const float*)d_in[0];
    const float* emb = (const float*)d_in[1];
    float* out = (float*)d_out;
    float* ws  = (float*)d_ws;

    _Float16* cbh  = (_Float16*)(ws + WS_CBH);
    float* cbT     = ws + WS_CBT;
    float* rinv    = ws + WS_RINV;
    float* mrowp   = ws + WS_MROW;
    int* idxw      = (int*)(ws + WS_IDX);
    int* flagcnt   = (int*)(ws + WS_FLAGCNT);
    int* flaglist  = (int*)(ws + WS_FLAGLIST);
    float* counts  = ws + WS_COUNTS;
    float* psum    = ws + WS_PSUM;
    float* mpart   = ws + WS_MPART;
    float* ppart   = ws + WS_PPART;
    float* cb32    = out + OUT_CB;
    float* zq      = out + OUT_ZQ;

    // scratch aliased into the zq output region (overwritten by k_zqg/k_recheck)
    _Float16* znorm      = (_Float16*)(zq + ZS_ZNORM);
    float* pm            = zq + ZS_PM;
    unsigned short* paux = (unsigned short*)(zq + ZS_PAUX);
    _Float16* psh        = (_Float16*)(zq + ZS_PSH);

    // flagcnt + counts are contiguous: single memset
    hipMemsetAsync(flagcnt, 0, (16 + NE) * sizeof(float), stream);

    k_cb      <<<512, 256, 0, stream>>>(emb, cbh, cb32, cbT);
    k_prep    <<<1024, 256, 0, stream>>>(z, znorm);
    k_s1      <<<2048, 256, 0, stream>>>(znorm, cbh, pm, paux, psh);
    k_comb    <<<256, 256, 0, stream>>>(pm, paux, psh, rinv, mrowp, idxw,
                                        flagcnt, flaglist, counts);
    k_s2      <<<1024, 256, 0, stream>>>(znorm, cbh, rinv, ppart);
    k_zqg     <<<4096, 256, 0, stream>>>(cb32, idxw, zq);
    k_recheck <<<512, 256, 0, stream>>>(z, cbT, cb32, flagcnt, flaglist,
                                        mrowp, counts, zq);
    k_red     <<<72, 256, 0, stream>>>(ppart, mrowp, psum, mpart);
    k_final   <<<1, 1024, 0, stream>>>(counts, psum, mpart, out);
}

// Round 12
// 159.165 us; speedup vs baseline: 1.2547x; 1.1289x over previous
//
#include <hip/hip_runtime.h>
#include <math.h>

#define NROWS 65536
#define ED 64
#define NE 2048
#define TAU 3e-4f
#define LOG2E 1.44269504089f
#define LN2 0.69314718056f
#define TAUS (TAU * LOG2E)

typedef _Float16 f16x8 __attribute__((ext_vector_type(8)));
typedef float f32x4 __attribute__((ext_vector_type(4)));

// fast 2^x: exactly one v_exp_f32 (no libcall fixup; inputs are in-range)
#if __has_builtin(__builtin_amdgcn_exp2f)
__device__ __forceinline__ float fexp2(float x) { return __builtin_amdgcn_exp2f(x); }
#else
__device__ __forceinline__ float fexp2(float x) {
    float r;
    asm("v_exp_f32 %0, %1" : "=v"(r) : "v"(x));
    return r;
}
#endif

// ---- workspace layout (float offsets): total ~2.9MB ----
#define WS_CBH      0        // fp16[2048*64] = 65536 float slots
#define WS_CBT      65536    // float[64*2048] transposed codebook
#define WS_RINV     196608   // float[65536]
#define WS_MROW     262144   // float[65536]
#define WS_IDX      327680   // int[65536]
#define WS_FLAGCNT  393216   // int[1] (+15 pad)
#define WS_COUNTS   393232   // float[2048]   (contiguous with flagcnt: one memset)
#define WS_FLAGLIST 395280   // int[65536]
#define WS_PSUM     460816   // float[2048]
#define WS_MPART    462864   // float[64]
#define WS_PPART    462928   // float[128*2048]

// ---- output layout (float offsets): z_q_st, commit, kl, lb, cb, perplexity ----
#define OUT_ZQ     0
#define OUT_COMMIT 4194304
#define OUT_KL     4194305
#define OUT_LB     4194306
#define OUT_CB     4194307
#define OUT_PERP   4325379

// ---- scratch inside the zq output region (fully overwritten later) ----
#define ZS_ZNORM   0         // fp16[65536*64]  -> 2097152 float slots
#define ZS_PM      2097152   // float[16*65536] -> 1048576 slots
#define ZS_PAUX    3145728   // u16[16*65536]   -> 524288 slots
#define ZS_PSH     3670016   // fp16[16*65536]  -> 524288 slots (ends at 4194304)

__global__ void k_cb(const float* __restrict__ emb, _Float16* __restrict__ cbh,
                     float* __restrict__ cbo, float* __restrict__ cbT) {
    int t = blockIdx.x * blockDim.x + threadIdx.x;
    int row = t >> 6;
    int lane = t & 63;
    if (row >= NE) return;
    float v = emb[row * ED + lane];
    float sq = v * v;
#pragma unroll
    for (int off = 32; off > 0; off >>= 1) sq += __shfl_xor(sq, off);
    float c = v * (1.0f / fmaxf(sqrtf(sq), 1e-12f));
    cbo[row * ED + lane] = c;
    cbh[row * ED + lane] = (_Float16)c;
    cbT[(size_t)lane * NE + row] = c;     // transposed copy for k_recheck
}

// Normalize z rows -> fp16 znorm, PRE-SCALED by log2(e) so exp(d)=v_exp(mfma out).
__global__ void k_prep(const float* __restrict__ z, _Float16* __restrict__ znorm) {
    const int tid = threadIdx.x;
    const int lane = tid & 63;
    const int w = tid >> 6;
    const int row = blockIdx.x * 64 + w * 16 + (lane >> 2);
    const int q = lane & 3;
    const float4* zp = (const float4*)(z + (size_t)row * ED + q * 16);
    const float4 a = zp[0], b = zp[1], c = zp[2], d = zp[3];
    float sq = a.x*a.x + a.y*a.y + a.z*a.z + a.w*a.w
             + b.x*b.x + b.y*b.y + b.z*b.z + b.w*b.w
             + c.x*c.x + c.y*c.y + c.z*c.z + c.w*c.w
             + d.x*d.x + d.y*d.y + d.z*d.z + d.w*d.w;
    sq += __shfl_xor(sq, 1);
    sq += __shfl_xor(sq, 2);
    const float r = LOG2E / fmaxf(sqrtf(sq), 1e-12f);
    f16x8 h0, h1;
    h0[0]=(_Float16)(a.x*r); h0[1]=(_Float16)(a.y*r); h0[2]=(_Float16)(a.z*r); h0[3]=(_Float16)(a.w*r);
    h0[4]=(_Float16)(b.x*r); h0[5]=(_Float16)(b.y*r); h0[6]=(_Float16)(b.z*r); h0[7]=(_Float16)(b.w*r);
    h1[0]=(_Float16)(c.x*r); h1[1]=(_Float16)(c.y*r); h1[2]=(_Float16)(c.z*r); h1[3]=(_Float16)(c.w*r);
    h1[4]=(_Float16)(d.x*r); h1[5]=(_Float16)(d.y*r); h1[6]=(_Float16)(d.z*r); h1[7]=(_Float16)(d.w*r);
    f16x8* dst = (f16x8*)(znorm + (size_t)row * ED + q * 16);
    dst[0] = h0; dst[1] = h1;
}

// Stats kernel: barrier-free, 4-wave blocks, cap 85 (no spill at 84 natural).
// Wave owns 128 codewords (A-frags resident). Scaled domain: c = d*log2e.
__launch_bounds__(256, 3)
__global__ void k_s1(const _Float16* __restrict__ znorm, const _Float16* __restrict__ cbh,
                     float* __restrict__ pm, unsigned short* __restrict__ paux,
                     _Float16* __restrict__ psh) {
    const int tid = threadIdx.x;
    const int lane = tid & 63;
    const int w = tid >> 6;               // 0..3
    const int l15 = lane & 15;
    const int lg = lane >> 4;
    const int gw = blockIdx.x * 4 + w;    // 0..8191
    const int g = gw & 15;                // codeword group (128 cw)
    const int split = gw >> 4;            // 0..511 (128 rows each)
    const int cwbase = g * 128;

    f16x8 af[8][2];
#pragma unroll
    for (int jf = 0; jf < 8; ++jf) {
        const _Float16* ap = cbh + (size_t)(cwbase + jf * 16 + l15) * ED + lg * 8;
        af[jf][0] = *(const f16x8*)(ap);
        af[jf][1] = *(const f16x8*)(ap + 32);
    }

    for (int t = 0; t < 4; ++t) {
        const int rbA = split * 128 + t * 32;
        const _Float16* bpA = znorm + (size_t)(rbA + l15) * ED + lg * 8;
        const _Float16* bpB = bpA + 16 * ED;
        const f16x8 bA0 = *(const f16x8*)(bpA);
        const f16x8 bA1 = *(const f16x8*)(bpA + 32);
        const f16x8 bB0 = *(const f16x8*)(bpB);
        const f16x8 bB1 = *(const f16x8*)(bpB + 32);
        float mA = -4.f, m2A = -4.f, sA0 = 0.f, sA1 = 0.f;
        float mB = -4.f, m2B = -4.f, sB0 = 0.f, sB1 = 0.f;
        int miA = 0, miB = 0;
#pragma unroll
        for (int jf = 0; jf < 8; ++jf) {
            f32x4 cA = (f32x4){0.f, 0.f, 0.f, 0.f};
            cA = __builtin_amdgcn_mfma_f32_16x16x32_f16(af[jf][0], bA0, cA, 0, 0, 0);
            cA = __builtin_amdgcn_mfma_f32_16x16x32_f16(af[jf][1], bA1, cA, 0, 0, 0);
            f32x4 cB = (f32x4){0.f, 0.f, 0.f, 0.f};
            cB = __builtin_amdgcn_mfma_f32_16x16x32_f16(af[jf][0], bB0, cB, 0, 0, 0);
            cB = __builtin_amdgcn_mfma_f32_16x16x32_f16(af[jf][1], bB1, cB, 0, 0, 0);
            const int cw0 = cwbase + jf * 16 + lg * 4;
#pragma unroll
            for (int i = 0; i < 4; ++i) {
                const float vA = cA[i];
                m2A = fmaxf(m2A, fminf(vA, mA));
                miA = (vA > mA) ? (cw0 + i) : miA;
                mA  = fmaxf(vA, mA);
                const float vB = cB[i];
                m2B = fmaxf(m2B, fminf(vB, mB));
                miB = (vB > mB) ? (cw0 + i) : miB;
                mB  = fmaxf(vB, mB);
                if (i & 1) { sA1 += fexp2(vA); sB1 += fexp2(vB); }
                else       { sA0 += fexp2(vA); sB0 += fexp2(vB); }
            }
        }
        float sA = sA0 + sA1, sB = sB0 + sB1;
#pragma unroll
        for (int d = 16; d <= 32; d <<= 1) {
            float om = __shfl_xor(mA, d);
            float om2 = __shfl_xor(m2A, d);
            int   oi = __shfl_xor(miA, d);
            sA += __shfl_xor(sA, d);
            float nm2 = fmaxf(fmaxf(m2A, om2), fminf(mA, om));
            bool take = (om > mA) || (om == mA && oi < miA);
            miA = take ? oi : miA;  mA = take ? om : mA;  m2A = nm2;
            om = __shfl_xor(mB, d);
            om2 = __shfl_xor(m2B, d);
            oi = __shfl_xor(miB, d);
            sB += __shfl_xor(sB, d);
            nm2 = fmaxf(fmaxf(m2B, om2), fminf(mB, om));
            take = (om > mB) || (om == mB && oi < miB);
            miB = take ? oi : miB;  mB = take ? om : mB;  m2B = nm2;
        }
        if (lane < 16) {
            int row = rbA + lane;
            pm[(size_t)g * NROWS + row] = mA;
            paux[(size_t)g * NROWS + row] =
                (unsigned short)(((mA - m2A < TAUS) ? 2048 : 0) | miA);
            psh[(size_t)g * NROWS + row] = (_Float16)sA;
            row += 16;
            pm[(size_t)g * NROWS + row] = mB;
            paux[(size_t)g * NROWS + row] =
                (unsigned short)(((mB - m2B < TAUS) ? 2048 : 0) | miB);
            psh[(size_t)g * NROWS + row] = (_Float16)sB;
        }
    }
}

// Per-row combine of the 16 group partials (scaled domain; unscale mrow by ln2).
__global__ void k_comb(const float* __restrict__ pm, const unsigned short* __restrict__ paux,
                       const _Float16* __restrict__ psh, float* __restrict__ rinv,
                       float* __restrict__ mrow, int* __restrict__ idxw,
                       int* __restrict__ flagcnt, int* __restrict__ flaglist,
                       float* __restrict__ counts) {
    const int row = blockIdx.x * 256 + threadIdx.x;
    float mg[16];
    unsigned short ax[16];
    float s = 0.f;
#pragma unroll
    for (int g = 0; g < 16; ++g) {
        mg[g] = pm[(size_t)g * NROWS + row];
        ax[g] = paux[(size_t)g * NROWS + row];
        s += (float)psh[(size_t)g * NROWS + row];
    }
    float bm = -4.f; int bi = 0;
#pragma unroll
    for (int g = 0; g < 16; ++g) {
        if (mg[g] > bm) { bm = mg[g]; bi = ax[g] & 2047; }
    }
    int near = 0; bool fl = false;
#pragma unroll
    for (int g = 0; g < 16; ++g) {
        const bool nr = (mg[g] >= bm - TAUS);
        near += nr ? 1 : 0;
        fl = fl || (nr && (ax[g] & 2048));
    }
    rinv[row] = 1.0f / s;
    mrow[row] = bm * LN2;
    idxw[row] = bi;
    if (fl || near >= 2) {
        int e = atomicAdd(flagcnt, 1);
        flaglist[e] = row;
    } else {
        atomicAdd(&counts[bi], 1.0f);
    }
}

// p accumulation: 4-wave blocks, cap 85; 4 codeword tiles resident, 4 chains.
__launch_bounds__(256, 3)
__global__ void k_s2(const _Float16* __restrict__ znorm, const _Float16* __restrict__ cbh,
                     const float* __restrict__ rinv, float* __restrict__ ppart) {
    const int tid = threadIdx.x;
    const int lane = tid & 63;
    const int w = tid >> 6;               // 0..3
    const int l15 = lane & 15;
    const int lg = lane >> 4;
    const int gw = blockIdx.x * 4 + w;    // 0..4095
    const int cwg = gw & 31;              // 64-cw group
    const int split = gw >> 5;            // 0..127 (512 rows each)

    f16x8 bf[4][2];
#pragma unroll
    for (int jf = 0; jf < 4; ++jf) {
        const _Float16* bp = cbh + (size_t)(cwg * 64 + jf * 16 + l15) * ED + lg * 8;
        bf[jf][0] = *(const f16x8*)(bp);
        bf[jf][1] = *(const f16x8*)(bp + 32);
    }
    float pc[4] = {0.f, 0.f, 0.f, 0.f};

    for (int t = 0; t < 32; ++t) {
        const int rowbase = split * 512 + t * 16;
        const _Float16* ap = znorm + (size_t)(rowbase + l15) * ED + lg * 8;
        const f16x8 a0 = *(const f16x8*)(ap);
        const f16x8 a1 = *(const f16x8*)(ap + 32);
        const int r0 = rowbase + lg * 4;
        const float rv0 = rinv[r0], rv1 = rinv[r0 + 1];
        const float rv2 = rinv[r0 + 2], rv3 = rinv[r0 + 3];
#pragma unroll
        for (int jf = 0; jf < 4; ++jf) {
            f32x4 c = (f32x4){0.f, 0.f, 0.f, 0.f};
            c = __builtin_amdgcn_mfma_f32_16x16x32_f16(a0, bf[jf][0], c, 0, 0, 0);
            c = __builtin_amdgcn_mfma_f32_16x16x32_f16(a1, bf[jf][1], c, 0, 0, 0);
            pc[jf] += fexp2(c[0]) * rv0 + fexp2(c[1]) * rv1
                    + fexp2(c[2]) * rv2 + fexp2(c[3]) * rv3;
        }
    }
#pragma unroll
    for (int jf = 0; jf < 4; ++jf) {
        pc[jf] += __shfl_xor(pc[jf], 16);
        pc[jf] += __shfl_xor(pc[jf], 32);
    }
    if (lg == 0) {
        float* pp = ppart + (size_t)split * NE + cwg * 64;
#pragma unroll
        for (int jf = 0; jf < 4; ++jf) pp[jf * 16 + l15] = pc[jf];
    }
}

// z_q gather (fully overwrites the zq scratch region). 16 threads per row.
__global__ void k_zqg(const float* __restrict__ cb32, const int* __restrict__ idxw,
                      float* __restrict__ zq) {
    const int r = blockIdx.x * 16 + (threadIdx.x >> 4);
    const int q = threadIdx.x & 15;
    const int j = idxw[r];
    ((float4*)(zq + (size_t)r * ED))[q] = ((const float4*)(cb32 + (size_t)j * ED))[q];
}

// Exact fp32 re-scan, LDS-tiled mini-GEMM: 8 flagged rows per block-tile.
// Thread t owns codeword columns {q*256+t}; coalesced cbT reads; z in LDS.
__launch_bounds__(256, 2)
__global__ void k_recheck(const float* __restrict__ z, const float* __restrict__ cbT,
                          const float* __restrict__ cb32,
                          const int* __restrict__ flagcnt, const int* __restrict__ flaglist,
                          float* __restrict__ mrow, float* __restrict__ counts,
                          float* __restrict__ zq) {
    __shared__ float zn[8][ED];
    __shared__ int   rowids[8];
    __shared__ float rbv[8][4];
    __shared__ int   rbi[8][4];
    const int n = *flagcnt;
    const int tid = threadIdx.x, lane = tid & 63, wv = tid >> 6;
    for (int base = blockIdx.x * 8; base < n; base += 512 * 8) {
        // ---- load + normalize up to 8 flagged rows (wave wv -> rows 2wv, 2wv+1) ----
#pragma unroll
        for (int rr = wv * 2; rr < wv * 2 + 2; ++rr) {
            const int e = base + rr;
            int row = -1;
            float v = 0.f;
            if (e < n) { row = flaglist[e]; v = z[(size_t)row * ED + lane]; }
            float sq = v * v;
#pragma unroll
            for (int d = 32; d > 0; d >>= 1) sq += __shfl_xor(sq, d);
            zn[rr][lane] = v * (1.0f / fmaxf(sqrtf(sq), 1e-12f));
            if (lane == 0) rowids[rr] = row;
        }
        __syncthreads();                      // (A) zn/rowids ready
        // ---- accumulate 8 rows x 8 columns per thread ----
        float acc[8][8];
#pragma unroll
        for (int r = 0; r < 8; ++r)
#pragma unroll
            for (int q = 0; q < 8; ++q) acc[r][q] = 0.f;
        for (int k = 0; k < ED; ++k) {
            float cv[8];
            const float* cr = cbT + (size_t)k * NE + tid;
#pragma unroll
            for (int q = 0; q < 8; ++q) cv[q] = cr[q * 256];
#pragma unroll
            for (int r = 0; r < 8; ++r) {
                const float zk = zn[r][k];
#pragma unroll
                for (int q = 0; q < 8; ++q)
                    acc[r][q] = fmaf(zk, cv[q], acc[r][q]);
            }
        }
        // ---- per-row argmax: thread-local over 8 cols, then wave, then block ----
#pragma unroll
        for (int r = 0; r < 8; ++r) {
            float best = -2.f; int bj = 0;
#pragma unroll
            for (int q = 0; q < 8; ++q) {     // ascending j per thread
                const float vv = acc[r][q];
                const int j = q * 256 + tid;
                bj = (vv > best) ? j : bj;
                best = fmaxf(vv, best);
            }
#pragma unroll
            for (int d = 1; d < 64; d <<= 1) {
                const float o = __shfl_xor(best, d);
                const int oj = __shfl_xor(bj, d);
                const bool tk = (o > best) || (o == best && oj < bj);
                best = tk ? o : best;
                bj = tk ? oj : bj;
            }
            if (lane == 0) { rbv[r][wv] = best; rbi[r][wv] = bj; }
        }
        __syncthreads();                      // (B) wave partials ready
        if (wv == 0 && lane < 8) {
            const int r = lane;
            float bv = rbv[r][0]; int bj = rbi[r][0];
#pragma unroll
            for (int u = 1; u < 4; ++u) {
                const float o = rbv[r][u]; const int oj = rbi[r][u];
                const bool tk = (o > bv) || (o == bv && oj < bj);
                bv = tk ? o : bv; bj = tk ? oj : bj;
            }
            rbi[r][0] = bj;                   // publish final
            const int row = rowids[r];
            if (row >= 0) {
                mrow[row] = bv;
                atomicAdd(&counts[bj], 1.0f);
            }
        }
        __syncthreads();                      // (C) final selection ready
        // ---- rewrite z_q rows (wave wv -> rows 2wv, 2wv+1) ----
#pragma unroll
        for (int rr = wv * 2; rr < wv * 2 + 2; ++rr) {
            const int row = rowids[rr];
            if (row >= 0) {
                const int bj = rbi[rr][0];
                zq[(size_t)row * ED + lane] = cb32[(size_t)bj * ED + lane];
            }
        }
    }
}

// Reductions: blocks 0..7 sum ppart columns (128 slices); blocks 8..71 sum mrow.
__global__ void k_red(const float* __restrict__ ppart, const float* __restrict__ mrow,
                      float* __restrict__ psum, float* __restrict__ mpart) {
    const int tid = threadIdx.x;
    if (blockIdx.x < 8) {
        const int col = blockIdx.x * 256 + tid;
        float s = 0.f;
        for (int sl = 0; sl < 128; ++sl) s += ppart[(size_t)sl * NE + col];
        psum[col] = s;
    } else {
        __shared__ float lds[4];
        const int b = blockIdx.x - 8;     // 0..63
        const int r0 = b * 1024;
        float s = 0.f;
        for (int r = r0 + tid; r < r0 + 1024; r += 256) s += mrow[r];
        const int lane = tid & 63, wv = tid >> 6;
#pragma unroll
        for (int d = 32; d > 0; d >>= 1) s += __shfl_xor(s, d);
        if (lane == 0) lds[wv] = s;
        __syncthreads();
        if (tid == 0) mpart[b] = lds[0] + lds[1] + lds[2] + lds[3];
    }
}

__device__ __forceinline__ float block_reduce_1024(float v, float* lds, int lane, int wid) {
#pragma unroll
    for (int off = 32; off > 0; off >>= 1) v += __shfl_xor(v, off);
    if (lane == 0) lds[wid] = v;
    __syncthreads();
    float r = 0.f;
    if (wid == 0) {
        r = (lane < 16) ? lds[lane] : 0.f;
#pragma unroll
        for (int off = 8; off > 0; off >>= 1) r += __shfl_xor(r, off);
    }
    __syncthreads();
    return r;
}

__global__ void k_final(const float* __restrict__ counts, const float* __restrict__ psum,
                        const float* __restrict__ mpart, float* __restrict__ out) {
    __shared__ float lds[16];
    const int tid = threadIdx.x;          // 1024
    const int lane = tid & 63, wid = tid >> 6;
    float sm = (tid < 64) ? mpart[tid] : 0.f;
    float kl = 0.f, lb = 0.f, H = 0.f;
    const float LOGNE = logf((float)NE);
    for (int j = tid; j < NE; j += 1024) {
        const float p = psum[j] * (1.0f / NROWS);
        const float em = counts[j] * (1.0f / NROWS);
        kl += p * (logf(p) + LOGNE);
        lb += em * p;
        H += em * logf(em + 1e-6f);
    }
    sm = block_reduce_1024(sm, lds, lane, wid);
    kl = block_reduce_1024(kl, lds, lane, wid);
    lb = block_reduce_1024(lb, lds, lane, wid);
    H  = block_reduce_1024(H,  lds, lane, wid);
    if (tid == 0) {
        out[OUT_COMMIT] = 1.25f * (1.0f - sm * (1.0f / NROWS));
        out[OUT_KL] = kl;
        out[OUT_LB] = lb;
        out[OUT_PERP] = expf(-H);
    }
}

extern "C" void kernel_launch(void* const* d_in, const int* in_sizes, int n_in,
                              void* d_out, int out_size, void* d_ws, size_t ws_size,
                              hipStream_t stream) {
    const float* z   = (const float*)d_in[0];
    const float* emb = (const float*)d_in[1];
    float* out = (float*)d_out;
    float* ws  = (float*)d_ws;

    _Float16* cbh  = (_Float16*)(ws + WS_CBH);
    float* cbT     = ws + WS_CBT;
    float* rinv    = ws + WS_RINV;
    float* mrowp   = ws + WS_MROW;
    int* idxw      = (int*)(ws + WS_IDX);
    int* flagcnt   = (int*)(ws + WS_FLAGCNT);
    int* flaglist  = (int*)(ws + WS_FLAGLIST);
    float* counts  = ws + WS_COUNTS;
    float* psum    = ws + WS_PSUM;
    float* mpart   = ws + WS_MPART;
    float* ppart   = ws + WS_PPART;
    float* cb32    = out + OUT_CB;
    float* zq      = out + OUT_ZQ;

    // scratch aliased into the zq output region (overwritten by k_zqg/k_recheck)
    _Float16* znorm      = (_Float16*)(zq + ZS_ZNORM);
    float* pm            = zq + ZS_PM;
    unsigned short* paux = (unsigned short*)(zq + ZS_PAUX);
    _Float16* psh        = (_Float16*)(zq + ZS_PSH);

    // flagcnt + counts are contiguous: single memset
    hipMemsetAsync(flagcnt, 0, (16 + NE) * sizeof(float), stream);

    k_cb      <<<512, 256, 0, stream>>>(emb, cbh, cb32, cbT);
    k_prep    <<<1024, 256, 0, stream>>>(z, znorm);
    k_s1      <<<2048, 256, 0, stream>>>(znorm, cbh, pm, paux, psh);
    k_comb    <<<256, 256, 0, stream>>>(pm, paux, psh, rinv, mrowp, idxw,
                                        flagcnt, flaglist, counts);
    k_s2      <<<1024, 256, 0, stream>>>(znorm, cbh, rinv, ppart);
    k_zqg     <<<4096, 256, 0, stream>>>(cb32, idxw, zq);
    k_recheck <<<512, 256, 0, stream>>>(z, cbT, cb32, flagcnt, flaglist,
                                        mrowp, counts, zq);
    k_red     <<<72, 256, 0, stream>>>(ppart, mrowp, psum, mpart);
    k_final   <<<1, 1024, 0, stream>>>(counts, psum, mpart, out);
}